// Round 8
// baseline (331.913 us; speedup 1.0000x reference)
//
#include <hip/hip_runtime.h>

typedef unsigned short u16;
using bf16x8 = __attribute__((ext_vector_type(8))) short;
using bf16x4 = __attribute__((ext_vector_type(4))) short;
using f32x4  = __attribute__((ext_vector_type(4))) float;

#define ATTN_NEG (-3.0e38f)

#if __has_builtin(__builtin_amdgcn_mfma_f32_16x16x16_bf16)
__device__ __forceinline__ f32x4 mfma16(bf16x4 a, bf16x4 b, f32x4 c) {
  return __builtin_amdgcn_mfma_f32_16x16x16_bf16(a, b, c, 0, 0, 0);
}
#elif __has_builtin(__builtin_amdgcn_mfma_f32_16x16x16bf16_1k)
__device__ __forceinline__ f32x4 mfma16(bf16x4 a, bf16x4 b, f32x4 c) {
  return __builtin_amdgcn_mfma_f32_16x16x16bf16_1k(a, b, c, 0, 0, 0);
}
#else
__device__ __forceinline__ f32x4 mfma16(bf16x4 a, bf16x4 b, f32x4 c) {
  asm volatile("v_mfma_f32_16x16x16_bf16 %0, %1, %2, %3"
               : "=v"(c) : "v"(a), "v"(b), "v"(c));
  return c;
}
#endif

__device__ __forceinline__ u16 f2bf_rne(float f) {
  unsigned int u = __float_as_uint(f);
  u += 0x7fffu + ((u >> 16) & 1u);
  return (u16)(u >> 16);
}

__device__ __forceinline__ void load_lds16(const u16* g, u16* l) {
  using gp = const __attribute__((address_space(1))) unsigned int*;
  using lp = __attribute__((address_space(3))) unsigned int*;
  __builtin_amdgcn_global_load_lds((gp)g, (lp)l, 16, 0, 0);
}

// ---------------- fused prep: x convert + 4 weight transposes ----------------
__device__ __forceinline__ void transpose_body(const float* __restrict__ in,
                                               u16* __restrict__ out, int K, int N,
                                               int bx, int by, int tid) {
  __shared__ float tile[32][33];
  int tx = tid & 31, ty = tid >> 5;  // 32 x 8
  int x0 = bx * 32, y0 = by * 32;
  #pragma unroll
  for (int i = 0; i < 32; i += 8)
    tile[ty + i][tx] = in[(size_t)(y0 + ty + i) * N + x0 + tx];
  __syncthreads();
  #pragma unroll
  for (int i = 0; i < 32; i += 8)
    out[(size_t)(x0 + ty + i) * K + y0 + tx] = f2bf_rne(tile[tx][ty + i]);
}

__global__ __launch_bounds__(256) void prep_kernel(const float* __restrict__ x,
                                                   const float* __restrict__ wq,
                                                   const float* __restrict__ wk,
                                                   const float* __restrict__ wv,
                                                   const float* __restrict__ wo,
                                                   u16* xb, u16* wqt, u16* wkt, u16* wvt,
                                                   u16* wot) {
  int bid = blockIdx.x, tid = threadIdx.x;
  if (bid < 8192) {
    int i = bid * 1024 + tid * 4;
    float4 v = *(const float4*)(x + i);
    u16* p = xb + i;
    p[0] = f2bf_rne(v.x); p[1] = f2bf_rne(v.y); p[2] = f2bf_rne(v.z); p[3] = f2bf_rne(v.w);
  } else if (bid < 12288) {
    int t = bid - 8192;
    transpose_body(wq, wqt, 2048, 2048, t & 63, t >> 6, tid);
  } else if (bid < 13312) {
    int t = bid - 12288;
    transpose_body(wk, wkt, 2048, 512, t & 15, t >> 4, tid);
  } else if (bid < 14336) {
    int t = bid - 13312;
    transpose_body(wv, wvt, 2048, 512, t & 15, t >> 4, tid);
  } else {
    int t = bid - 14336;
    transpose_body(wo, wot, 2048, 2048, t & 63, t >> 6, tid);
  }
}

// ---------------- m97-style GEMM: C[M,N] = A[M,K] * Bt[N,K]^T ----------------
// MODE 0: bf16. MODE 1: bf16 transposed k-permuted (V^T). MODE 2: fp32. MODE 3: bf16*kappa (Q).
template <int MODE>
__device__ __forceinline__ void gemm_tile(const u16* __restrict__ A, const u16* __restrict__ Bt,
                                          void* __restrict__ Cv, int M, int N, int K,
                                          int bx, int by, char* smem) {
  u16* As = (u16*)smem;           // [128][32]
  u16* Bs = (u16*)(smem + 8192);  // [128][32]
  const int tid  = threadIdx.x;
  const int wave = tid >> 6, lane = tid & 63;
  const int quad = lane >> 4, l16 = lane & 15;
  const int m0 = by * 128, n0 = bx * 128;
  const int wm = (wave >> 1) * 64, wn = (wave & 1) * 64;
  f32x4 acc[4][4] = {};

  const int srow = (wave << 4) + (lane >> 2);
  const int scol = (lane & 3) << 3;
  const u16* ga0 = A  + (size_t)(m0 + srow) * K + scol;
  const u16* gb0 = Bt + (size_t)(n0 + srow) * K + scol;
  u16* la = As + wave * 512;
  u16* lb = Bs + wave * 512;

  for (int k0 = 0; k0 < K; k0 += 32) {
    __syncthreads();
    load_lds16(ga0 + k0, la);
    load_lds16(ga0 + (size_t)64 * K + k0, la + 2048);
    load_lds16(gb0 + k0, lb);
    load_lds16(gb0 + (size_t)64 * K + k0, lb + 2048);
    __syncthreads();
    bf16x8 af[4], bfr[4];
    #pragma unroll
    for (int i = 0; i < 4; ++i) {
      af[i]  = *(const bf16x8*)(As + (wm + i * 16 + l16) * 32 + quad * 8);
      bfr[i] = *(const bf16x8*)(Bs + (wn + i * 16 + l16) * 32 + quad * 8);
    }
    #pragma unroll
    for (int mi = 0; mi < 4; ++mi)
      #pragma unroll
      for (int ni = 0; ni < 4; ++ni)
        acc[mi][ni] = __builtin_amdgcn_mfma_f32_16x16x32_bf16(af[mi], bfr[ni], acc[mi][ni], 0, 0, 0);
  }

  if constexpr (MODE == 0 || MODE == 3) {
    const float sc = (MODE == 3) ? 0.12751742f : 1.0f;  // log2(e)/sqrt(128)
    u16* Cb = (u16*)Cv;
    #pragma unroll
    for (int mi = 0; mi < 4; ++mi)
      #pragma unroll
      for (int ni = 0; ni < 4; ++ni) {
        int row = m0 + wm + mi * 16 + quad * 4;
        int col = n0 + wn + ni * 16 + l16;
        #pragma unroll
        for (int r = 0; r < 4; ++r)
          Cb[(size_t)(row + r) * N + col] = f2bf_rne(acc[mi][ni][r] * sc);
      }
  } else if constexpr (MODE == 1) {
    // V^T with k-permuted 32-chunks: pos(k) = ((k&15)>>2)*8 + ((k>>4)&1)*4 + (k&3)
    u16* Cb = (u16*)Cv;
    #pragma unroll
    for (int mi = 0; mi < 4; ++mi)
      #pragma unroll
      for (int ni = 0; ni < 4; ++ni) {
        int col = n0 + wn + ni * 16 + l16;
        #pragma unroll
        for (int r = 0; r < 4; ++r) {
          int row = m0 + wm + mi * 16 + quad * 4 + r;
          int bb = row >> 11, s = row & 2047;
          int c = s & 31;
          int cp = ((c & 15) >> 2) * 8 + ((c >> 4) & 1) * 4 + (c & 3);
          Cb[((size_t)(bb * 512 + col)) * 2048 + (s & ~31) + cp] = f2bf_rne(acc[mi][ni][r]);
        }
      }
  } else {
    float* Cf = (float*)Cv;
    #pragma unroll
    for (int mi = 0; mi < 4; ++mi)
      #pragma unroll
      for (int ni = 0; ni < 4; ++ni) {
        int row = m0 + wm + mi * 16 + quad * 4;
        int col = n0 + wn + ni * 16 + l16;
        #pragma unroll
        for (int r = 0; r < 4; ++r)
          Cf[(size_t)(row + r) * N + col] = acc[mi][ni][r];
      }
  }
}

__global__ __launch_bounds__(256) void qkv_gemm(const u16* xb, const u16* wqt, const u16* wkt,
                                                const u16* wvt, u16* Qb, u16* Kb, u16* Vt) {
  extern __shared__ char smem[];
  int bx = blockIdx.x, by = blockIdx.y;
  if (bx < 16)
    gemm_tile<3>(xb, wqt, Qb, 4096, 2048, 2048, bx, by, smem);
  else if (bx < 20)
    gemm_tile<0>(xb, wkt, Kb, 4096, 512, 2048, bx - 16, by, smem);
  else
    gemm_tile<1>(xb, wvt, Vt, 4096, 512, 2048, bx - 20, by, smem);
}

template <int MODE>
__global__ __launch_bounds__(256) void gemm_kernel(const u16* A, const u16* Bt, void* C,
                                                   int M, int N, int K) {
  extern __shared__ char smem[];
  gemm_tile<MODE>(A, Bt, C, M, N, K, blockIdx.x, blockIdx.y, smem);
}

// ---------------- flash attention v8: 32 q-rows/wave, k-parity wave split ----------------
// Pair P (waves 2P, 2P+1) serves q-rows [tile*64+P*32, +32) (2 frags); waves split k-chunks
// by parity. No online max => partial (O,l) over disjoint k-ranges add exactly; merged once
// per tile-half via LDS (aliases staging buffers).
// K buf region (ks*2+h): slot lane*16B = K[kt0+16h+l16][ks*32+quad*8..+8]
// V buf region f:        slot lane*16B = Vt_perm[16f+l16][kt0+quad*8..+8]

__device__ __forceinline__ void stage_kv(const u16* __restrict__ Kg, const u16* __restrict__ Vg,
                                         int kt0, u16* __restrict__ kbuf, u16* __restrict__ vbuf,
                                         int wave, int quad, int l16) {
  #pragma unroll
  for (int h = 0; h < 2; ++h)
    load_lds16(Kg + (size_t)(kt0 + h * 16 + l16) * 512 + wave * 32 + quad * 8,
               kbuf + (wave * 2 + h) * 512);
  #pragma unroll
  for (int i = 0; i < 2; ++i) {
    int f = wave * 2 + i;
    load_lds16(Vg + (size_t)(16 * f + l16) * 2048 + kt0 + quad * 8, vbuf + f * 512);
  }
}

template <bool MASKED>
__device__ __forceinline__ void attn_compute2(const u16* __restrict__ kbuf,
                                              const u16* __restrict__ vbuf,
                                              int kt0, int q0p, int quad, int l16,
                                              const bf16x8 (&qf)[2][4], f32x4 (&o)[2][8],
                                              float (&l_lane)[2]) {
  const int slot = (quad * 16 + l16) * 8;  // lane*16B
  bf16x8 kf[8];
  #pragma unroll
  for (int kk = 0; kk < 8; ++kk) kf[kk] = *(const bf16x8*)(kbuf + kk * 512 + slot);

  f32x4 sa[2][2] = {};
  #pragma unroll
  for (int j = 0; j < 2; ++j)
    #pragma unroll
    for (int h = 0; h < 2; ++h)
      #pragma unroll
      for (int ks = 0; ks < 4; ++ks)
        sa[j][h] = __builtin_amdgcn_mfma_f32_16x16x32_bf16(kf[ks * 2 + h], qf[j][ks],
                                                           sa[j][h], 0, 0, 0);

  bf16x4 pa[2][2];
  #pragma unroll
  for (int j = 0; j < 2; ++j)
    #pragma unroll
    for (int h = 0; h < 2; ++h) {
      #pragma unroll
      for (int r = 0; r < 4; ++r) {
        float s = sa[j][h][r];
        if (MASKED) {
          int kpos = kt0 + 16 * h + quad * 4 + r;
          s = (kpos <= q0p + j * 16 + l16) ? s : ATTN_NEG;
        }
        float p = __builtin_amdgcn_exp2f(s);
        l_lane[j] += p;
        pa[j][h][r] = (short)f2bf_rne(p);
      }
    }

  #pragma unroll
  for (int f = 0; f < 8; ++f) {
    bf16x8 v8 = *(const bf16x8*)(vbuf + f * 512 + slot);
    bf16x4 vlo = {v8[0], v8[1], v8[2], v8[3]};
    bf16x4 vhi = {v8[4], v8[5], v8[6], v8[7]};
    #pragma unroll
    for (int j = 0; j < 2; ++j) {
      o[j][f] = mfma16(pa[j][0], vlo, o[j][f]);
      o[j][f] = mfma16(pa[j][1], vhi, o[j][f]);
    }
  }
}

// Blocks: (pair 0..15, head, b); 4 waves; pair tp does 64-row tiles tp and 31-tp.
__global__ __launch_bounds__(256, 2) void attn_kernel(const u16* __restrict__ Qb,
                                                      const u16* __restrict__ Kb,
                                                      const u16* __restrict__ Vt,
                                                      u16* __restrict__ Ob) {
  constexpr int S = 2048;
  const int b = blockIdx.z, h = blockIdx.y, g = h >> 2, tp = blockIdx.x;
  const int tid = threadIdx.x;
  const int wave = tid >> 6, lane = tid & 63, quad = lane >> 4, l16 = lane & 15;
  const int pair = wave >> 1, wpar = wave & 1;
  __shared__ alignas(16) u16 sraw[16384];  // 32KB: K/V staging, aliased as merge buffer
  __shared__ float lmrg[2][128];
  __shared__ float lbuf[2][2][16];

  u16* Ktb = sraw;          // Kt[buf] = sraw + buf*4096
  u16* Vlb = sraw + 8192;   // Vl[buf] = sraw + 8192 + buf*4096

  const u16* Kg = Kb + (size_t)b * S * 512 + g * 128;
  const u16* Vg = Vt + (size_t)(b * 512 + g * 128) * 2048;

  for (int half = 0; half < 2; ++half) {
    const int tile = (half == 0) ? tp : 31 - tp;
    const int q0p = tile * 64 + pair * 32;
    const int nsteps = 2 * tile + 2;
    const int s_diag = 2 * tile + pair;
    const int par = wpar ^ half;  // flip parity across halves to balance chunk counts

    bf16x8 qf[2][4];
    #pragma unroll
    for (int j = 0; j < 2; ++j) {
      const u16* qrow = Qb + (size_t)(b * S + q0p + j * 16 + l16) * 2048 + h * 128 + quad * 8;
      #pragma unroll
      for (int ks = 0; ks < 4; ++ks) qf[j][ks] = *(const bf16x8*)(qrow + ks * 32);
    }

    f32x4 o[2][8] = {};
    float l_lane[2] = {0.f, 0.f};

    __syncthreads();  // previous half's merge reads done before re-staging
    stage_kv(Kg, Vg, 0, Ktb, Vlb, wave, quad, l16);

    for (int s = 0; s < nsteps; ++s) {
      __syncthreads();  // buf[s&1] staged & visible
      const u16* kb = Ktb + (s & 1) * 4096;
      const u16* vb = Vlb + (s & 1) * 4096;
      if (s + 1 < nsteps)
        stage_kv(Kg, Vg, (s + 1) * 32, Ktb + ((s + 1) & 1) * 4096,
                 Vlb + ((s + 1) & 1) * 4096, wave, quad, l16);
      if (((s & 1) == par) && s <= s_diag) {
        if (s == s_diag)
          attn_compute2<true>(kb, vb, s * 32, q0p, quad, l16, qf, o, l_lane);
        else
          attn_compute2<false>(kb, vb, s * 32, q0p, quad, l16, qf, o, l_lane);
      }
    }

    // -------- pairwise merge (exact: no max normalization) --------
    __syncthreads();  // all staging-buffer readers done; safe to alias
    if (wpar) {
      float* mb = (float*)sraw + pair * 4096 + lane * 64;
      #pragma unroll
      for (int j = 0; j < 2; ++j)
        #pragma unroll
        for (int f = 0; f < 8; ++f)
          *(f32x4*)(mb + j * 32 + f * 4) = o[j][f];
      lmrg[pair][lane] = l_lane[0];
      lmrg[pair][64 + lane] = l_lane[1];
    }
    __syncthreads();
    if (!wpar) {
      const float* mb = (const float*)sraw + pair * 4096 + lane * 64;
      #pragma unroll
      for (int j = 0; j < 2; ++j) {
        #pragma unroll
        for (int f = 0; f < 8; ++f) {
          f32x4 t = *(const f32x4*)(mb + j * 32 + f * 4);
          #pragma unroll
          for (int r = 0; r < 4; ++r) o[j][f][r] += t[r];
        }
        float lt = l_lane[j] + lmrg[pair][j * 64 + lane];
        lt += __shfl_xor(lt, 16);
        lt += __shfl_xor(lt, 32);
        if (quad == 0) lbuf[pair][j][l16] = lt;
      }
      __builtin_amdgcn_wave_barrier();
      #pragma unroll
      for (int j = 0; j < 2; ++j) {
        float il[4];
        #pragma unroll
        for (int r = 0; r < 4; ++r) il[r] = 1.f / lbuf[pair][j][quad * 4 + r];
        u16* orow = Ob + (size_t)(b * S + q0p + j * 16 + quad * 4) * 2048 + h * 128 + l16;
        #pragma unroll
        for (int f = 0; f < 8; ++f)
          #pragma unroll
          for (int r = 0; r < 4; ++r)
            orow[(size_t)r * 2048 + f * 16] = f2bf_rne(o[j][f][r] * il[r]);
      }
    }
  }
}

extern "C" void kernel_launch(void* const* d_in, const int* in_sizes, int n_in,
                              void* d_out, int out_size, void* d_ws, size_t ws_size,
                              hipStream_t stream) {
  const float* x  = (const float*)d_in[0];
  const float* wq = (const float*)d_in[1];
  const float* wk = (const float*)d_in[2];
  const float* wv = (const float*)d_in[3];
  const float* wo = (const float*)d_in[4];
  float* out = (float*)d_out;
  char* ws = (char*)d_ws;

  u16* xb  = (u16*)(ws);
  u16* wqt = (u16*)(ws + 16777216);
  u16* wkt = (u16*)(ws + 25165824);
  u16* wvt = (u16*)(ws + 27262976);
  u16* wot = (u16*)(ws + 29360128);
  u16* Qb  = (u16*)(ws + 37748736);
  u16* Kb  = (u16*)(ws + 54525952);
  u16* Vt  = (u16*)(ws + 58720256);
  u16* Ab  = (u16*)(ws + 62914560);

  prep_kernel<<<18432, 256, 0, stream>>>(x, wq, wk, wv, wo, xb, wqt, wkt, wvt, wot);
  qkv_gemm<<<dim3(24, 32), 256, 16384, stream>>>(xb, wqt, wkt, wvt, Qb, Kb, Vt);
  attn_kernel<<<dim3(16, 16, 2), 256, 0, stream>>>(Qb, Kb, Vt, Ab);
  gemm_kernel<2><<<dim3(16, 32), 256, 16384, stream>>>(Ab, wot, out, 4096, 2048, 2048);
}

// Round 9
// 301.016 us; speedup vs baseline: 1.1026x; 1.1026x over previous
//
#include <hip/hip_runtime.h>

typedef unsigned short u16;
using bf16x8 = __attribute__((ext_vector_type(8))) short;
using bf16x4 = __attribute__((ext_vector_type(4))) short;
using f32x4  = __attribute__((ext_vector_type(4))) float;

#define ATTN_NEG (-3.0e38f)

#if __has_builtin(__builtin_amdgcn_mfma_f32_16x16x16_bf16)
__device__ __forceinline__ f32x4 mfma16(bf16x4 a, bf16x4 b, f32x4 c) {
  return __builtin_amdgcn_mfma_f32_16x16x16_bf16(a, b, c, 0, 0, 0);
}
#elif __has_builtin(__builtin_amdgcn_mfma_f32_16x16x16bf16_1k)
__device__ __forceinline__ f32x4 mfma16(bf16x4 a, bf16x4 b, f32x4 c) {
  return __builtin_amdgcn_mfma_f32_16x16x16bf16_1k(a, b, c, 0, 0, 0);
}
#else
__device__ __forceinline__ f32x4 mfma16(bf16x4 a, bf16x4 b, f32x4 c) {
  asm volatile("v_mfma_f32_16x16x16_bf16 %0, %1, %2, %3"
               : "=v"(c) : "v"(a), "v"(b), "v"(c));
  return c;
}
#endif

__device__ __forceinline__ u16 f2bf_rne(float f) {
  unsigned int u = __float_as_uint(f);
  u += 0x7fffu + ((u >> 16) & 1u);
  return (u16)(u >> 16);
}

__device__ __forceinline__ void load_lds16(const u16* g, u16* l) {
  using gp = const __attribute__((address_space(1))) unsigned int*;
  using lp = __attribute__((address_space(3))) unsigned int*;
  __builtin_amdgcn_global_load_lds((gp)g, (lp)l, 16, 0, 0);
}

// ---------------- fused prep: x convert + 4 weight transposes ----------------
__device__ __forceinline__ void transpose_body(const float* __restrict__ in,
                                               u16* __restrict__ out, int K, int N,
                                               int bx, int by, int tid) {
  __shared__ float tile[32][33];
  int tx = tid & 31, ty = tid >> 5;  // 32 x 8
  int x0 = bx * 32, y0 = by * 32;
  #pragma unroll
  for (int i = 0; i < 32; i += 8)
    tile[ty + i][tx] = in[(size_t)(y0 + ty + i) * N + x0 + tx];
  __syncthreads();
  #pragma unroll
  for (int i = 0; i < 32; i += 8)
    out[(size_t)(x0 + ty + i) * K + y0 + tx] = f2bf_rne(tile[tx][ty + i]);
}

__global__ __launch_bounds__(256) void prep_kernel(const float* __restrict__ x,
                                                   const float* __restrict__ wq,
                                                   const float* __restrict__ wk,
                                                   const float* __restrict__ wv,
                                                   const float* __restrict__ wo,
                                                   u16* xb, u16* wqt, u16* wkt, u16* wvt,
                                                   u16* wot) {
  int bid = blockIdx.x, tid = threadIdx.x;
  if (bid < 8192) {
    int i = bid * 1024 + tid * 4;
    float4 v = *(const float4*)(x + i);
    u16* p = xb + i;
    p[0] = f2bf_rne(v.x); p[1] = f2bf_rne(v.y); p[2] = f2bf_rne(v.z); p[3] = f2bf_rne(v.w);
  } else if (bid < 12288) {
    int t = bid - 8192;
    transpose_body(wq, wqt, 2048, 2048, t & 63, t >> 6, tid);
  } else if (bid < 13312) {
    int t = bid - 12288;
    transpose_body(wk, wkt, 2048, 512, t & 15, t >> 4, tid);
  } else if (bid < 14336) {
    int t = bid - 13312;
    transpose_body(wv, wvt, 2048, 512, t & 15, t >> 4, tid);
  } else {
    int t = bid - 14336;
    transpose_body(wo, wot, 2048, 2048, t & 63, t >> 6, tid);
  }
}

// ---------------- GEMM v2: BK=64 (two m97-layout 32-col halves per step) ----------------
// C[M,N] = A[M,K] * Bt[N,K]^T
// MODE 0: bf16. MODE 1: bf16 transposed k-permuted (V^T). MODE 2: fp32. MODE 3: bf16*kappa (Q).
// LDS: As/Bs each [2 halves][128 rows][32 cols] = 16 KB; half h layout identical to m97.
template <int MODE>
__device__ __forceinline__ void gemm_tile(const u16* __restrict__ A, const u16* __restrict__ Bt,
                                          void* __restrict__ Cv, int M, int N, int K,
                                          int bx, int by, char* smem) {
  u16* As = (u16*)smem;            // [2][128][32]
  u16* Bs = (u16*)(smem + 16384);  // [2][128][32]
  const int tid  = threadIdx.x;
  const int wave = tid >> 6, lane = tid & 63;
  const int quad = lane >> 4, l16 = lane & 15;
  const int m0 = by * 128, n0 = bx * 128;
  const int wm = (wave >> 1) * 64, wn = (wave & 1) * 64;
  f32x4 acc[4][4] = {};

  const int srow = lane >> 2;        // 0..15
  const int scol = (lane & 3) << 3;  // 0,8,16,24

  for (int k0 = 0; k0 < K; k0 += 64) {
    __syncthreads();
    #pragma unroll
    for (int h = 0; h < 2; ++h)
      #pragma unroll
      for (int i = 0; i < 2; ++i) {
        const int row = wave * 16 + i * 64;  // + srow per lane
        load_lds16(A  + (size_t)(m0 + row + srow) * K + k0 + h * 32 + scol,
                   As + h * 4096 + row * 32);
        load_lds16(Bt + (size_t)(n0 + row + srow) * K + k0 + h * 32 + scol,
                   Bs + h * 4096 + row * 32);
      }
    __syncthreads();
    #pragma unroll
    for (int h = 0; h < 2; ++h) {
      bf16x8 af[4], bfr[4];
      #pragma unroll
      for (int i = 0; i < 4; ++i) {
        af[i]  = *(const bf16x8*)(As + h * 4096 + (wm + i * 16 + l16) * 32 + quad * 8);
        bfr[i] = *(const bf16x8*)(Bs + h * 4096 + (wn + i * 16 + l16) * 32 + quad * 8);
      }
      #pragma unroll
      for (int mi = 0; mi < 4; ++mi)
        #pragma unroll
        for (int ni = 0; ni < 4; ++ni)
          acc[mi][ni] =
              __builtin_amdgcn_mfma_f32_16x16x32_bf16(af[mi], bfr[ni], acc[mi][ni], 0, 0, 0);
    }
  }

  if constexpr (MODE == 0 || MODE == 3) {
    const float sc = (MODE == 3) ? 0.12751742f : 1.0f;  // log2(e)/sqrt(128)
    u16* Cb = (u16*)Cv;
    #pragma unroll
    for (int mi = 0; mi < 4; ++mi)
      #pragma unroll
      for (int ni = 0; ni < 4; ++ni) {
        int row = m0 + wm + mi * 16 + quad * 4;
        int col = n0 + wn + ni * 16 + l16;
        #pragma unroll
        for (int r = 0; r < 4; ++r)
          Cb[(size_t)(row + r) * N + col] = f2bf_rne(acc[mi][ni][r] * sc);
      }
  } else if constexpr (MODE == 1) {
    // V^T with k-permuted 32-chunks: pos(k) = ((k&15)>>2)*8 + ((k>>4)&1)*4 + (k&3)
    u16* Cb = (u16*)Cv;
    #pragma unroll
    for (int mi = 0; mi < 4; ++mi)
      #pragma unroll
      for (int ni = 0; ni < 4; ++ni) {
        int col = n0 + wn + ni * 16 + l16;
        #pragma unroll
        for (int r = 0; r < 4; ++r) {
          int row = m0 + wm + mi * 16 + quad * 4 + r;
          int bb = row >> 11, s = row & 2047;
          int c = s & 31;
          int cp = ((c & 15) >> 2) * 8 + ((c >> 4) & 1) * 4 + (c & 3);
          Cb[((size_t)(bb * 512 + col)) * 2048 + (s & ~31) + cp] = f2bf_rne(acc[mi][ni][r]);
        }
      }
  } else {
    float* Cf = (float*)Cv;
    #pragma unroll
    for (int mi = 0; mi < 4; ++mi)
      #pragma unroll
      for (int ni = 0; ni < 4; ++ni) {
        int row = m0 + wm + mi * 16 + quad * 4;
        int col = n0 + wn + ni * 16 + l16;
        #pragma unroll
        for (int r = 0; r < 4; ++r)
          Cf[(size_t)(row + r) * N + col] = acc[mi][ni][r];
      }
  }
}

__global__ __launch_bounds__(256) void qkv_gemm(const u16* xb, const u16* wqt, const u16* wkt,
                                                const u16* wvt, u16* Qb, u16* Kb, u16* Vt) {
  extern __shared__ char smem[];
  int bx = blockIdx.x, by = blockIdx.y;
  if (bx < 16)
    gemm_tile<3>(xb, wqt, Qb, 4096, 2048, 2048, bx, by, smem);
  else if (bx < 20)
    gemm_tile<0>(xb, wkt, Kb, 4096, 512, 2048, bx - 16, by, smem);
  else
    gemm_tile<1>(xb, wvt, Vt, 4096, 512, 2048, bx - 20, by, smem);
}

template <int MODE>
__global__ __launch_bounds__(256) void gemm_kernel(const u16* A, const u16* Bt, void* C,
                                                   int M, int N, int K) {
  extern __shared__ char smem[];
  gemm_tile<MODE>(A, Bt, C, M, N, K, blockIdx.x, blockIdx.y, smem);
}

// ---------------- flash attention (R6-validated): S^T formulation, register P ----------------
// K LDS region (ks*2+h): slot lane*16B = K[kt0+16h+l16][ks*32+quad*8..+8]
// V LDS region f:        slot lane*16B = Vt_perm[16f+l16][kt0+quad*8..+8]

__device__ __forceinline__ void stage_kv(const u16* __restrict__ Kg, const u16* __restrict__ Vg,
                                         int kt0, u16* __restrict__ kbuf, u16* __restrict__ vbuf,
                                         int wave, int quad, int l16) {
  #pragma unroll
  for (int h = 0; h < 2; ++h)
    load_lds16(Kg + (size_t)(kt0 + h * 16 + l16) * 512 + wave * 32 + quad * 8,
               kbuf + (wave * 2 + h) * 512);
  #pragma unroll
  for (int i = 0; i < 2; ++i) {
    int f = wave * 2 + i;
    load_lds16(Vg + (size_t)(16 * f + l16) * 2048 + kt0 + quad * 8, vbuf + f * 512);
  }
}

template <bool MASKED>
__device__ __forceinline__ void attn_compute(const u16* __restrict__ kbuf,
                                             const u16* __restrict__ vbuf,
                                             int kt0, int q0w, int quad, int l16,
                                             const bf16x8 (&qf)[4], f32x4 (&o)[8],
                                             float& l_lane) {
  const int slot = (quad * 16 + l16) * 8;  // lane*16B
  bf16x8 kf[8];
  #pragma unroll
  for (int kk = 0; kk < 8; ++kk) kf[kk] = *(const bf16x8*)(kbuf + kk * 512 + slot);

  f32x4 sa[2] = {};
  #pragma unroll
  for (int h = 0; h < 2; ++h)
    #pragma unroll
    for (int ks = 0; ks < 4; ++ks)
      sa[h] = __builtin_amdgcn_mfma_f32_16x16x32_bf16(kf[ks * 2 + h], qf[ks], sa[h], 0, 0, 0);

  bf16x4 pa[2];
  #pragma unroll
  for (int h = 0; h < 2; ++h) {
    #pragma unroll
    for (int r = 0; r < 4; ++r) {
      float s = sa[h][r];
      if (MASKED) {
        int kpos = kt0 + 16 * h + quad * 4 + r;
        s = (kpos <= q0w + l16) ? s : ATTN_NEG;
      }
      float p = __builtin_amdgcn_exp2f(s);
      l_lane += p;
      pa[h][r] = (short)f2bf_rne(p);
    }
  }

  #pragma unroll
  for (int f = 0; f < 8; ++f) {
    bf16x8 v8 = *(const bf16x8*)(vbuf + f * 512 + slot);
    bf16x4 vlo = {v8[0], v8[1], v8[2], v8[3]};
    bf16x4 vhi = {v8[4], v8[5], v8[6], v8[7]};
    o[f] = mfma16(pa[0], vlo, o[f]);
    o[f] = mfma16(pa[1], vhi, o[f]);
  }
}

// Blocks: (pair 0..15, head, b); 4 waves x 16 q-rows = 64-row tiles; pair p does tiles p
// and 31-p -> uniform 66 steps; 512 blocks = 2 blocks/CU.
__global__ __launch_bounds__(256, 2) void attn_kernel(const u16* __restrict__ Qb,
                                                      const u16* __restrict__ Kb,
                                                      const u16* __restrict__ Vt,
                                                      u16* __restrict__ Ob) {
  constexpr int S = 2048;
  const int b = blockIdx.z, h = blockIdx.y, g = h >> 2, tp = blockIdx.x;
  const int tid = threadIdx.x;
  const int wave = tid >> 6, lane = tid & 63, quad = lane >> 4, l16 = lane & 15;
  __shared__ alignas(16) u16 Kt[2][4096];
  __shared__ alignas(16) u16 Vl[2][4096];
  __shared__ float lbuf[4][16];

  const u16* Kg = Kb + (size_t)b * S * 512 + g * 128;
  const u16* Vg = Vt + (size_t)(b * 512 + g * 128) * 2048;

  #pragma unroll
  for (int half = 0; half < 2; ++half) {
    const int tile = (half == 0) ? tp : 31 - tp;
    const int wrow = (half == 0) ? wave : 3 - wave;  // balance diagonal idle
    const int q0w = tile * 64 + wrow * 16;
    const int nsteps = 2 * tile + 2;
    const int s_diag = 2 * tile + (wrow >> 1);

    bf16x8 qf[4];
    const u16* qrow = Qb + (size_t)(b * S + q0w + l16) * 2048 + h * 128 + quad * 8;
    #pragma unroll
    for (int ks = 0; ks < 4; ++ks) qf[ks] = *(const bf16x8*)(qrow + ks * 32);

    f32x4 o[8] = {};
    float l_lane = 0.f;

    __syncthreads();  // previous half's readers done before re-staging buf0
    stage_kv(Kg, Vg, 0, Kt[0], Vl[0], wave, quad, l16);

    for (int s = 0; s < nsteps; ++s) {
      __syncthreads();  // buf[s&1] staged & visible
      if (s + 1 < nsteps)
        stage_kv(Kg, Vg, (s + 1) * 32, Kt[(s + 1) & 1], Vl[(s + 1) & 1], wave, quad, l16);
      if (s < s_diag)
        attn_compute<false>(Kt[s & 1], Vl[s & 1], s * 32, q0w, quad, l16, qf, o, l_lane);
      else if (s == s_diag)
        attn_compute<true>(Kt[s & 1], Vl[s & 1], s * 32, q0w, quad, l16, qf, o, l_lane);
      // s > s_diag: fully masked for this wave -> stage+barrier only
    }

    // total l per q=l16: sum over quads
    float lt = l_lane + __shfl_xor(l_lane, 16);
    lt += __shfl_xor(lt, 32);
    if (quad == 0) lbuf[wave][l16] = lt;
    __builtin_amdgcn_wave_barrier();
    float il[4];
    #pragma unroll
    for (int r = 0; r < 4; ++r) il[r] = 1.f / lbuf[wave][quad * 4 + r];

    u16* orow = Ob + (size_t)(b * S + q0w + quad * 4) * 2048 + h * 128 + l16;
    #pragma unroll
    for (int f = 0; f < 8; ++f)
      #pragma unroll
      for (int r = 0; r < 4; ++r)
        orow[(size_t)r * 2048 + f * 16] = f2bf_rne(o[f][r] * il[r]);
  }
}

extern "C" void kernel_launch(void* const* d_in, const int* in_sizes, int n_in,
                              void* d_out, int out_size, void* d_ws, size_t ws_size,
                              hipStream_t stream) {
  const float* x  = (const float*)d_in[0];
  const float* wq = (const float*)d_in[1];
  const float* wk = (const float*)d_in[2];
  const float* wv = (const float*)d_in[3];
  const float* wo = (const float*)d_in[4];
  float* out = (float*)d_out;
  char* ws = (char*)d_ws;

  u16* xb  = (u16*)(ws);
  u16* wqt = (u16*)(ws + 16777216);
  u16* wkt = (u16*)(ws + 25165824);
  u16* wvt = (u16*)(ws + 27262976);
  u16* wot = (u16*)(ws + 29360128);
  u16* Qb  = (u16*)(ws + 37748736);
  u16* Kb  = (u16*)(ws + 54525952);
  u16* Vt  = (u16*)(ws + 58720256);
  u16* Ab  = (u16*)(ws + 62914560);

  prep_kernel<<<18432, 256, 0, stream>>>(x, wq, wk, wv, wo, xb, wqt, wkt, wvt, wot);
  qkv_gemm<<<dim3(24, 32), 256, 32768, stream>>>(xb, wqt, wkt, wvt, Qb, Kb, Vt);
  attn_kernel<<<dim3(16, 16, 2), 256, 0, stream>>>(Qb, Kb, Vt, Ab);
  gemm_kernel<2><<<dim3(16, 32), 256, 32768, stream>>>(Ab, wot, out, 4096, 2048, 2048);
}